// Round 8
// baseline (46.088 us; speedup 1.0000x reference)
//
#include <hip/hip_runtime.h>
#include <cmath>

namespace {

constexpr int B_ = 128;
constexpr int N_ = 64;
constexpr int T_ = 512;
constexpr int K_ = 5;
constexpr int NBINS = 257;   // T/2 + 1
constexpr int PMAX = 2184;   // T*T // 120
constexpr int ROWS = 4;      // (b,n) rows per block, 1 per wave
constexpr int CHUNKS = N_ / ROWS;  // 16 mag-partial chunks per batch

struct cpx { float re, im; };
__device__ __forceinline__ cpx cadd(cpx a, cpx b) { return {a.re + b.re, a.im + b.im}; }
__device__ __forceinline__ cpx csub(cpx a, cpx b) { return {a.re - b.re, a.im - b.im}; }
__device__ __forceinline__ cpx cmul(cpx a, cpx b) {
  return {a.re * b.re - a.im * b.im, a.re * b.im + a.im * b.re};
}

// Full complex radix-8 DFT on NAMED scalars (no arrays -> no scratch risk).
// t_c = sum_w z_w * W8^{w*c}, W8 = e^{-2pi i/8}.
__device__ __forceinline__ void radix8(
    cpx z0, cpx z1, cpx z2, cpx z3, cpx z4, cpx z5, cpx z6, cpx z7,
    cpx& t0, cpx& t1, cpx& t2, cpx& t3, cpx& t4, cpx& t5, cpx& t6, cpx& t7) {
  const float c = 0.70710678118654752f;
  cpx a0 = cadd(z0, z4), a1 = csub(z0, z4);
  cpx a2 = cadd(z2, z6), a3 = csub(z2, z6);
  cpx a4 = cadd(z1, z5), a5 = csub(z1, z5);
  cpx a6 = cadd(z3, z7), a7 = csub(z3, z7);
  cpx b0 = cadd(a0, a2), b1 = csub(a0, a2);
  cpx b2 = cadd(a4, a6), b3 = csub(a4, a6);
  t0 = cadd(b0, b2);
  t4 = csub(b0, b2);
  t2 = {b1.re + b3.im, b1.im - b3.re};   // b1 - i*b3
  t6 = {b1.re - b3.im, b1.im + b3.re};   // b1 + i*b3
  cpx ua5  = {c * (a5.re + a5.im), c * (a5.im - a5.re)};  // u*a5,  u = c(1-i)
  cpx usa5 = {c * (a5.re - a5.im), c * (a5.re + a5.im)};  // u"*a5, u" = c(1+i)
  cpx ua7  = {c * (a7.re + a7.im), c * (a7.im - a7.re)};
  cpx usa7 = {c * (a7.re - a7.im), c * (a7.re + a7.im)};
  cpx mia3 = {a3.im, -a3.re};  // -i*a3
  cpx pia3 = {-a3.im, a3.re};  // +i*a3
  t1 = cadd(cadd(a1, ua5), csub(mia3, usa7));
  t3 = cadd(csub(a1, usa5), cadd(pia3, ua7));
  t5 = cadd(csub(a1, ua5), cadd(mia3, usa7));
  t7 = cadd(cadd(a1, usa5), csub(pia3, ua7));
}

// ---------------- Kernel A: radix-8^3 FFT magnitudes --------------------------
// grid = B_*CHUNKS, block = 256 (4 waves, 1 (b,n) row per wave).
// Fully de-arrayed: every intermediate is a named scalar with compile-time
// indexing, so nothing can fall into per-thread scratch (rule #20).
// LDS: SoA stride-9 planes (gcd(9,32)=1, 2-way alias = free); phase-3 mags
// reuse the dead bre plane.
__global__ __launch_bounds__(256, 6) void fft_mag_kernel(const float* __restrict__ x,
                                                         float* __restrict__ magp) {
  const int tid = threadIdx.x;
  const int w = tid >> 6;
  const int lane = tid & 63;
  const int row = blockIdx.x * ROWS + w;  // b*64 + n

  __shared__ float bre[ROWS][576];   // 64 rows x stride 9
  __shared__ float bim[ROWS][576];

  float* bre_w = &bre[w][0];
  float* bim_w = &bim[w][0];

  // ---- phase 1: real radix-8 over v (stride 64) + twiddle W512^{j*r}
  const float* src = x + ((size_t)row << 9);
  const int j = lane;
  {
    const float x0v = src[j], x1v = src[j + 64], x2v = src[j + 128], x3v = src[j + 192];
    const float x4v = src[j + 256], x5v = src[j + 320], x6v = src[j + 384], x7v = src[j + 448];
    const float c = 0.70710678118654752f;
    const float s04 = x0v + x4v, d04 = x0v - x4v;
    const float s26 = x2v + x6v, d26 = x2v - x6v;
    const float s15 = x1v + x5v, d15 = x1v - x5v;
    const float s37 = x3v + x7v, d37 = x3v - x7v;
    const float se = s04 + s26, so = s15 + s37;
    const float cm = c * (d15 - d37), cp = c * (d15 + d37);
    const cpx y0 = {se + so, 0.f};
    const cpx y1 = {d04 + cm, -(d26 + cp)};
    const cpx y2 = {s04 - s26, s37 - s15};
    const cpx y3 = {d04 - cm, d26 - cp};
    const cpx y4 = {se - so, 0.f};
    const cpx y5 = {d04 - cm, cp - d26};   // conj(y3)
    const cpx y6 = {s04 - s26, s15 - s37}; // conj(y2)
    const cpx y7 = {d04 + cm, d26 + cp};   // conj(y1)
    float sj, cj;
    __sincosf((float)j * 0.01227184630308513f /*2pi/512*/, &sj, &cj);
    const cpx wj = {cj, -sj};
    const int p = j * 9;
    cpx tw = wj, z;
    bre_w[p + 0] = y0.re;              bim_w[p + 0] = y0.im;
    z = cmul(y1, tw); bre_w[p + 1] = z.re; bim_w[p + 1] = z.im; tw = cmul(tw, wj);
    z = cmul(y2, tw); bre_w[p + 2] = z.re; bim_w[p + 2] = z.im; tw = cmul(tw, wj);
    z = cmul(y3, tw); bre_w[p + 3] = z.re; bim_w[p + 3] = z.im; tw = cmul(tw, wj);
    z = cmul(y4, tw); bre_w[p + 4] = z.re; bim_w[p + 4] = z.im; tw = cmul(tw, wj);
    z = cmul(y5, tw); bre_w[p + 5] = z.re; bim_w[p + 5] = z.im; tw = cmul(tw, wj);
    z = cmul(y6, tw); bre_w[p + 6] = z.re; bim_w[p + 6] = z.im; tw = cmul(tw, wj);
    z = cmul(y7, tw); bre_w[p + 7] = z.re; bim_w[p + 7] = z.im;
  }
  __syncthreads();

  // ---- phase 2: complex radix-8 over w (stride 8 in j) + twiddle W64^{i*c}
  // j = i + q*8 -> idx = j*9 + r = i*9 + r + q*72.
  cpx yv0, yv1, yv2, yv3, yv4, yv5, yv6, yv7;
  const int r2 = lane >> 3, i2 = lane & 7;
  {
    const int p = i2 * 9 + r2;
    const cpx zz0 = {bre_w[p +   0], bim_w[p +   0]};
    const cpx zz1 = {bre_w[p +  72], bim_w[p +  72]};
    const cpx zz2 = {bre_w[p + 144], bim_w[p + 144]};
    const cpx zz3 = {bre_w[p + 216], bim_w[p + 216]};
    const cpx zz4 = {bre_w[p + 288], bim_w[p + 288]};
    const cpx zz5 = {bre_w[p + 360], bim_w[p + 360]};
    const cpx zz6 = {bre_w[p + 432], bim_w[p + 432]};
    const cpx zz7 = {bre_w[p + 504], bim_w[p + 504]};
    cpx t0, t1, t2, t3, t4, t5, t6, t7;
    radix8(zz0, zz1, zz2, zz3, zz4, zz5, zz6, zz7,
           t0, t1, t2, t3, t4, t5, t6, t7);
    float si, ci;
    __sincosf((float)i2 * 0.09817477042468103f /*2pi/64*/, &si, &ci);
    const cpx wi = {ci, -si};
    cpx tw = wi;
    yv0 = t0;
    yv1 = cmul(t1, tw); tw = cmul(tw, wi);
    yv2 = cmul(t2, tw); tw = cmul(tw, wi);
    yv3 = cmul(t3, tw); tw = cmul(tw, wi);
    yv4 = cmul(t4, tw); tw = cmul(tw, wi);
    yv5 = cmul(t5, tw); tw = cmul(tw, wi);
    yv6 = cmul(t6, tw); tw = cmul(tw, wi);
    yv7 = cmul(t7, tw);
  }
  __syncthreads();  // all reads of z done before overwrite
  {
    // write yv_c at idx = (r*8+c)*9 + i = r*72 + c*9 + i
    const int p = r2 * 72 + i2;
    bre_w[p +  0] = yv0.re; bim_w[p +  0] = yv0.im;
    bre_w[p +  9] = yv1.re; bim_w[p +  9] = yv1.im;
    bre_w[p + 18] = yv2.re; bim_w[p + 18] = yv2.im;
    bre_w[p + 27] = yv3.re; bim_w[p + 27] = yv3.im;
    bre_w[p + 36] = yv4.re; bim_w[p + 36] = yv4.im;
    bre_w[p + 45] = yv5.re; bim_w[p + 45] = yv5.im;
    bre_w[p + 54] = yv6.re; bim_w[p + 54] = yv6.im;
    bre_w[p + 63] = yv7.re; bim_w[p + 63] = yv7.im;
  }
  __syncthreads();

  // ---- phase 3: final radix-8 over i -> X[64s + 8c + r]; only k <= 256 kept.
  // yy_i at idx = (r*8+c)*9 + i = r*72 + c*9 + i (consecutive i).
  {
    const int r3 = lane >> 3, c3 = lane & 7;
    const int p = r3 * 72 + c3 * 9;
    const cpx yy0 = {bre_w[p + 0], bim_w[p + 0]};
    const cpx yy1 = {bre_w[p + 1], bim_w[p + 1]};
    const cpx yy2 = {bre_w[p + 2], bim_w[p + 2]};
    const cpx yy3 = {bre_w[p + 3], bim_w[p + 3]};
    const cpx yy4 = {bre_w[p + 4], bim_w[p + 4]};
    const cpx yy5 = {bre_w[p + 5], bim_w[p + 5]};
    const cpx yy6 = {bre_w[p + 6], bim_w[p + 6]};
    const cpx yy7 = {bre_w[p + 7], bim_w[p + 7]};
    cpx X0, X1, X2, X3, X4, X5, X6, X7;
    radix8(yy0, yy1, yy2, yy3, yy4, yy5, yy6, yy7,
           X0, X1, X2, X3, X4, X5, X6, X7);
    __syncthreads();  // all phase-3 reads done before mag overwrites bre
    const int kb = (c3 << 3) + r3;  // 0..63
    bre_w[kb +   0] = sqrtf(X0.re * X0.re + X0.im * X0.im);
    bre_w[kb +  64] = sqrtf(X1.re * X1.re + X1.im * X1.im);
    bre_w[kb + 128] = sqrtf(X2.re * X2.re + X2.im * X2.im);
    bre_w[kb + 192] = sqrtf(X3.re * X3.re + X3.im * X3.im);
    if (kb == 0) bre_w[256] = sqrtf(X4.re * X4.re + X4.im * X4.im);
    // s >= 5 -> k > 256: never needed (conjugate mirror of kept bins)
  }
  __syncthreads();

  for (int bin = tid; bin < NBINS; bin += 256) {
    magp[(size_t)blockIdx.x * NBINS + bin] =
        bre[0][bin] + bre[1][bin] + bre[2][bin] + bre[3][bin];
  }
}

// ---------------- Kernel B: per-batch top-5 -> window sizes -------------------
// Separate dispatch on purpose: cross-workgroup magp handoff inside one
// dispatch raced on XCD L2 non-coherence (R5 failure). Kernel boundary is the
// safe publication point.
__global__ __launch_bounds__(64) void topk_scale_kernel(const float* __restrict__ magp,
                                                        int* __restrict__ scale) {
  const int b = blockIdx.x;
  const int lane = threadIdx.x;
  __shared__ float m[NBINS];
  for (int i = lane; i < NBINS; i += 64) {
    float s = -1.0f;
    if (i != 0) {
      s = 0.0f;
      for (int c = 0; c < CHUNKS; ++c)
        s += magp[(size_t)(b * CHUNKS + c) * NBINS + i];
    }
    m[i] = s;
  }
  __syncthreads();

  for (int kk = 0; kk < K_; ++kk) {
    float best = -1e30f;
    int bi = NBINS;
    for (int i = lane; i < NBINS; i += 64) {
      const float v = m[i];
      if (v > best || (v == best && i < bi)) { best = v; bi = i; }
    }
    for (int off = 32; off > 0; off >>= 1) {
      const float ov = __shfl_down(best, off);
      const int oi = __shfl_down(bi, off);
      if (ov > best || (ov == best && oi < bi)) { best = ov; bi = oi; }
    }
    bi = __shfl(bi, 0);
    if (lane == 0) {
      // scale = floor(512 / (i * 15/64)) = 32768 / (15*i), exact integer
      int sc = 32768 / (15 * bi);
      sc = sc < 1 ? 1 : (sc > PMAX ? PMAX : sc);
      scale[b * K_ + kk] = sc;
      m[bi] = -1e30f;
    }
    __syncthreads();
  }
}

// ---------------- Kernel C: single-barrier wave scan + windowed means ---------
// grid = B_*N_/ROWS, block = 256 (4 waves, one (b,n) row per wave).
__global__ __launch_bounds__(256) void trend_kernel(const float* __restrict__ x,
                                                    const int* __restrict__ scale,
                                                    float* __restrict__ out) {
  const int w = threadIdx.x >> 6;
  const int lane = threadIdx.x & 63;
  const int bn = blockIdx.x * ROWS + w;  // b*64 + n
  const int b = bn >> 6;

  __shared__ double P[ROWS][T_ + 1];  // 16.4 KB

  const float* src = x + ((size_t)bn << 9);
  const float4 v0 = *reinterpret_cast<const float4*>(src + (lane << 3));
  const float4 v1 = *reinterpret_cast<const float4*>(src + (lane << 3) + 4);

  double e0 = (double)v0.x;
  double e1 = e0 + (double)v0.y;
  double e2 = e1 + (double)v0.z;
  double e3 = e2 + (double)v0.w;
  double e4 = e3 + (double)v1.x;
  double e5 = e4 + (double)v1.y;
  double e6 = e5 + (double)v1.z;
  double e7 = e6 + (double)v1.w;  // inclusive prefix within the 8-chunk

  double v = e7;
  for (int off = 1; off < 64; off <<= 1) {
    const double o = __shfl_up(v, off);
    if (lane >= off) v += o;
  }
  const double base = v - e7;  // exclusive prefix of this lane's chunk

  double* Pw = P[w];
  if (lane == 0) Pw[0] = 0.0;
  const int p0 = (lane << 3) + 1;
  Pw[p0 + 0] = base + e0;
  Pw[p0 + 1] = base + e1;
  Pw[p0 + 2] = base + e2;
  Pw[p0 + 3] = base + e3;
  Pw[p0 + 4] = base + e4;
  Pw[p0 + 5] = base + e5;
  Pw[p0 + 6] = base + e6;
  Pw[p0 + 7] = base + e7;
  __syncthreads();

  const double x0 = Pw[1];
  const double xl = Pw[T_] - Pw[T_ - 1];

  float* outbn = out + (((size_t)bn * K_) << 9);
#pragma unroll
  for (int kk = 0; kk < K_; ++kk) {
    const int k = scale[b * K_ + kk];
    const int p = (k - 1) >> 1;
    const int Lm1 = T_ + 2 * p - k;  // L - 1
    const double invk = 1.0 / (double)k;
#pragma unroll
    for (int u = 0; u < 8; ++u) {
      const int t = lane + (u << 6);
      const int tc = t < Lm1 ? t : Lm1;
      const int lo = tc - p;       // window = [lo, lo+k) in original coords
      const int hi = lo + k;
      const int cl = lo < 0 ? -lo : 0;        // left edge replications of x[0]
      const int cr = hi > T_ ? hi - T_ : 0;   // right edge replications of x[511]
      const int loc = lo < 0 ? 0 : lo;
      const int hic = hi > T_ ? T_ : hi;
      const double sum = Pw[hic] - Pw[loc] + (double)cl * x0 + (double)cr * xl;
      outbn[(kk << 9) + t] = (float)(sum * invk);
    }
  }
}

}  // namespace

extern "C" void kernel_launch(void* const* d_in, const int* in_sizes, int n_in,
                              void* d_out, int out_size, void* d_ws, size_t ws_size,
                              hipStream_t stream) {
  const float* x = (const float*)d_in[0];
  float* out = (float*)d_out;

  // mag partials in d_out (2048*257 floats = 2.1 MB); trend_kernel fully
  // overwrites d_out afterwards in stream order, so this is safe scratch.
  float* magp = out;
  int* scale = (int*)d_ws;  // 2.5 KB, must survive while C runs

  hipLaunchKernelGGL(fft_mag_kernel, dim3(B_ * CHUNKS), dim3(256), 0, stream, x, magp);
  hipLaunchKernelGGL(topk_scale_kernel, dim3(B_), dim3(64), 0, stream, magp, scale);
  hipLaunchKernelGGL(trend_kernel, dim3(B_ * N_ / ROWS), dim3(256), 0, stream, x, scale, out);
}

// Round 9
// 42.097 us; speedup vs baseline: 1.0948x; 1.0948x over previous
//
#include <hip/hip_runtime.h>
#include <cmath>

namespace {

constexpr int B_ = 128;
constexpr int N_ = 64;
constexpr int T_ = 512;
constexpr int K_ = 5;
constexpr int NBINS = 257;   // T/2 + 1
constexpr int PMAX = 2184;   // T*T // 120
constexpr int ROWS = 4;      // trend: (b,n) rows per block, 1 per wave
constexpr int FROWS = 8;     // fft: rows per block (2 per wave)
constexpr int CHUNKS = N_ / FROWS;  // 8 mag-partial chunks per batch

struct cpx { float re, im; };
__device__ __forceinline__ cpx cadd(cpx a, cpx b) { return {a.re + b.re, a.im + b.im}; }
__device__ __forceinline__ cpx csub(cpx a, cpx b) { return {a.re - b.re, a.im - b.im}; }
__device__ __forceinline__ cpx cmul(cpx a, cpx b) {
  return {a.re * b.re - a.im * b.im, a.re * b.im + a.im * b.re};
}

// Full complex radix-8 DFT on named scalars. t_c = sum_w z_w * W8^{w*c}.
__device__ __forceinline__ void radix8(
    cpx z0, cpx z1, cpx z2, cpx z3, cpx z4, cpx z5, cpx z6, cpx z7,
    cpx& t0, cpx& t1, cpx& t2, cpx& t3, cpx& t4, cpx& t5, cpx& t6, cpx& t7) {
  const float c = 0.70710678118654752f;
  cpx a0 = cadd(z0, z4), a1 = csub(z0, z4);
  cpx a2 = cadd(z2, z6), a3 = csub(z2, z6);
  cpx a4 = cadd(z1, z5), a5 = csub(z1, z5);
  cpx a6 = cadd(z3, z7), a7 = csub(z3, z7);
  cpx b0 = cadd(a0, a2), b1 = csub(a0, a2);
  cpx b2 = cadd(a4, a6), b3 = csub(a4, a6);
  t0 = cadd(b0, b2);
  t4 = csub(b0, b2);
  t2 = {b1.re + b3.im, b1.im - b3.re};   // b1 - i*b3
  t6 = {b1.re - b3.im, b1.im + b3.re};   // b1 + i*b3
  cpx ua5  = {c * (a5.re + a5.im), c * (a5.im - a5.re)};  // u*a5,  u = c(1-i)
  cpx usa5 = {c * (a5.re - a5.im), c * (a5.re + a5.im)};  // u"*a5, u" = c(1+i)
  cpx ua7  = {c * (a7.re + a7.im), c * (a7.im - a7.re)};
  cpx usa7 = {c * (a7.re - a7.im), c * (a7.re + a7.im)};
  cpx mia3 = {a3.im, -a3.re};
  cpx pia3 = {-a3.im, a3.re};
  t1 = cadd(cadd(a1, ua5), csub(mia3, usa7));
  t3 = cadd(csub(a1, usa5), cadd(pia3, ua7));
  t5 = cadd(csub(a1, ua5), cadd(mia3, usa7));
  t7 = cadd(cadd(a1, usa5), csub(pia3, ua7));
}

// Phase-1 real radix-8 + W512^{jr} twiddle + store to plane (SoA stride 9).
__device__ __forceinline__ void p1_row(const float* __restrict__ src, int j,
                                       cpx wj, float* __restrict__ br,
                                       float* __restrict__ bi) {
  const float x0v = src[j], x1v = src[j + 64], x2v = src[j + 128], x3v = src[j + 192];
  const float x4v = src[j + 256], x5v = src[j + 320], x6v = src[j + 384], x7v = src[j + 448];
  const float c = 0.70710678118654752f;
  const float s04 = x0v + x4v, d04 = x0v - x4v;
  const float s26 = x2v + x6v, d26 = x2v - x6v;
  const float s15 = x1v + x5v, d15 = x1v - x5v;
  const float s37 = x3v + x7v, d37 = x3v - x7v;
  const float se = s04 + s26, so = s15 + s37;
  const float cm = c * (d15 - d37), cp = c * (d15 + d37);
  const cpx y0 = {se + so, 0.f};
  const cpx y1 = {d04 + cm, -(d26 + cp)};
  const cpx y2 = {s04 - s26, s37 - s15};
  const cpx y3 = {d04 - cm, d26 - cp};
  const cpx y4 = {se - so, 0.f};
  const cpx y5 = {d04 - cm, cp - d26};   // conj(y3)
  const cpx y6 = {s04 - s26, s15 - s37}; // conj(y2)
  const cpx y7 = {d04 + cm, d26 + cp};   // conj(y1)
  const int p = j * 9;
  cpx tw = wj, z;
  br[p + 0] = y0.re;              bi[p + 0] = y0.im;
  z = cmul(y1, tw); br[p + 1] = z.re; bi[p + 1] = z.im; tw = cmul(tw, wj);
  z = cmul(y2, tw); br[p + 2] = z.re; bi[p + 2] = z.im; tw = cmul(tw, wj);
  z = cmul(y3, tw); br[p + 3] = z.re; bi[p + 3] = z.im; tw = cmul(tw, wj);
  z = cmul(y4, tw); br[p + 4] = z.re; bi[p + 4] = z.im; tw = cmul(tw, wj);
  z = cmul(y5, tw); br[p + 5] = z.re; bi[p + 5] = z.im; tw = cmul(tw, wj);
  z = cmul(y6, tw); br[p + 6] = z.re; bi[p + 6] = z.im; tw = cmul(tw, wj);
  z = cmul(y7, tw); br[p + 7] = z.re; bi[p + 7] = z.im;
}

// Phase-2: read stride-72 column, radix-8, W64^{ic} twiddle, write transposed.
__device__ __forceinline__ void p2_row(int r2, int i2, cpx wi,
                                       float* __restrict__ br,
                                       float* __restrict__ bi) {
  const int p = i2 * 9 + r2;
  const cpx zz0 = {br[p +   0], bi[p +   0]};
  const cpx zz1 = {br[p +  72], bi[p +  72]};
  const cpx zz2 = {br[p + 144], bi[p + 144]};
  const cpx zz3 = {br[p + 216], bi[p + 216]};
  const cpx zz4 = {br[p + 288], bi[p + 288]};
  const cpx zz5 = {br[p + 360], bi[p + 360]};
  const cpx zz6 = {br[p + 432], bi[p + 432]};
  const cpx zz7 = {br[p + 504], bi[p + 504]};
  cpx t0, t1, t2, t3, t4, t5, t6, t7;
  radix8(zz0, zz1, zz2, zz3, zz4, zz5, zz6, zz7, t0, t1, t2, t3, t4, t5, t6, t7);
  cpx tw = wi;
  cpx y1 = cmul(t1, tw); tw = cmul(tw, wi);
  cpx y2 = cmul(t2, tw); tw = cmul(tw, wi);
  cpx y3 = cmul(t3, tw); tw = cmul(tw, wi);
  cpx y4 = cmul(t4, tw); tw = cmul(tw, wi);
  cpx y5 = cmul(t5, tw); tw = cmul(tw, wi);
  cpx y6 = cmul(t6, tw); tw = cmul(tw, wi);
  cpx y7 = cmul(t7, tw);
  // write y_c at (r2*8+c)*9 + i2 ; within-wave RAW/WAR ordered by lgkmcnt
  const int q = r2 * 72 + i2;
  br[q +  0] = t0.re; bi[q +  0] = t0.im;
  br[q +  9] = y1.re; bi[q +  9] = y1.im;
  br[q + 18] = y2.re; bi[q + 18] = y2.im;
  br[q + 27] = y3.re; bi[q + 27] = y3.im;
  br[q + 36] = y4.re; bi[q + 36] = y4.im;
  br[q + 45] = y5.re; bi[q + 45] = y5.im;
  br[q + 54] = y6.re; bi[q + 54] = y6.im;
  br[q + 63] = y7.re; bi[q + 63] = y7.im;
}

// Phase-3: final radix-8 -> |X| for k = 64s + 8c + r, k <= 256.
__device__ __forceinline__ void p3_row(int r3, int c3,
                                       const float* __restrict__ br,
                                       const float* __restrict__ bi,
                                       float& m0, float& m1, float& m2,
                                       float& m3, float& m4) {
  const int p = r3 * 72 + c3 * 9;
  const cpx yy0 = {br[p + 0], bi[p + 0]};
  const cpx yy1 = {br[p + 1], bi[p + 1]};
  const cpx yy2 = {br[p + 2], bi[p + 2]};
  const cpx yy3 = {br[p + 3], bi[p + 3]};
  const cpx yy4 = {br[p + 4], bi[p + 4]};
  const cpx yy5 = {br[p + 5], bi[p + 5]};
  const cpx yy6 = {br[p + 6], bi[p + 6]};
  const cpx yy7 = {br[p + 7], bi[p + 7]};
  cpx X0, X1, X2, X3, X4, X5, X6, X7;
  radix8(yy0, yy1, yy2, yy3, yy4, yy5, yy6, yy7, X0, X1, X2, X3, X4, X5, X6, X7);
  m0 = sqrtf(X0.re * X0.re + X0.im * X0.im);
  m1 = sqrtf(X1.re * X1.re + X1.im * X1.im);
  m2 = sqrtf(X2.re * X2.re + X2.im * X2.im);
  m3 = sqrtf(X3.re * X3.re + X3.im * X3.im);
  m4 = sqrtf(X4.re * X4.re + X4.im * X4.im);
}

// ---------------- Kernel A: radix-8^3 FFT magnitudes, 2 rows/wave -------------
// grid = B_*N_/FROWS = 1024, block = 256 (4 waves, 2 rows each).
// Waves own LDS planes exclusively -> NO intermediate barriers; the only
// __syncthreads is before the cross-wave magp sum. Twiddles shared by the
// row-pair; mags of the pair combined into the even plane.
__global__ __launch_bounds__(256, 4) void fft_mag_kernel(const float* __restrict__ x,
                                                         float* __restrict__ magp) {
  const int tid = threadIdx.x;
  const int w = tid >> 6;
  const int lane = tid & 63;
  const int rowA = blockIdx.x * FROWS + 2 * w;  // b*64 + n

  __shared__ float bre[FROWS][576];
  __shared__ float bim[FROWS][576];

  float* brA = &bre[2 * w][0];
  float* biA = &bim[2 * w][0];
  float* brB = &bre[2 * w + 1][0];
  float* biB = &bim[2 * w + 1][0];

  const float* srcA = x + ((size_t)rowA << 9);
  const float* srcB = srcA + T_;

  // phase 1 (shared twiddle W512^j)
  {
    float sj, cj;
    __sincosf((float)lane * 0.01227184630308513f /*2pi/512*/, &sj, &cj);
    const cpx wj = {cj, -sj};
    p1_row(srcA, lane, wj, brA, biA);
    p1_row(srcB, lane, wj, brB, biB);
  }

  // phase 2 (shared twiddle W64^i)
  const int r2 = lane >> 3, i2 = lane & 7;
  {
    float si, ci;
    __sincosf((float)i2 * 0.09817477042468103f /*2pi/64*/, &si, &ci);
    const cpx wi = {ci, -si};
    p2_row(r2, i2, wi, brA, biA);
    p2_row(r2, i2, wi, brB, biB);
  }

  // phase 3: |X_A| + |X_B| -> even plane [0..256]
  {
    float a0, a1, a2, a3, a4, b0, b1, b2, b3, b4;
    p3_row(r2, i2, brA, biA, a0, a1, a2, a3, a4);
    p3_row(r2, i2, brB, biB, b0, b1, b2, b3, b4);
    const int kb = (i2 << 3) + r2;  // 0..63
    brA[kb +   0] = a0 + b0;
    brA[kb +  64] = a1 + b1;
    brA[kb + 128] = a2 + b2;
    brA[kb + 192] = a3 + b3;
    if (kb == 0) brA[256] = a4 + b4;
  }
  __syncthreads();  // the only cross-wave handoff

  for (int bin = tid; bin < NBINS; bin += 256) {
    magp[(size_t)blockIdx.x * NBINS + bin] =
        bre[0][bin] + bre[2][bin] + bre[4][bin] + bre[6][bin];
  }
}

// ---------------- Kernel B: per-batch top-5 -> window sizes -------------------
// Separate dispatch on purpose: cross-workgroup magp handoff inside one
// dispatch raced on XCD L2 non-coherence (R5 failure).
__global__ __launch_bounds__(64) void topk_scale_kernel(const float* __restrict__ magp,
                                                        int* __restrict__ scale) {
  const int b = blockIdx.x;
  const int lane = threadIdx.x;
  __shared__ float m[NBINS];
  for (int i = lane; i < NBINS; i += 64) {
    float s = -1.0f;
    if (i != 0) {
      s = 0.0f;
      for (int c = 0; c < CHUNKS; ++c)
        s += magp[(size_t)(b * CHUNKS + c) * NBINS + i];
    }
    m[i] = s;
  }
  __syncthreads();

  for (int kk = 0; kk < K_; ++kk) {
    float best = -1e30f;
    int bi = NBINS;
    for (int i = lane; i < NBINS; i += 64) {
      const float v = m[i];
      if (v > best || (v == best && i < bi)) { best = v; bi = i; }
    }
    for (int off = 32; off > 0; off >>= 1) {
      const float ov = __shfl_down(best, off);
      const int oi = __shfl_down(bi, off);
      if (ov > best || (ov == best && oi < bi)) { best = ov; bi = oi; }
    }
    bi = __shfl(bi, 0);
    if (lane == 0) {
      // scale = floor(512 / (i * 15/64)) = 32768 / (15*i), exact integer
      int sc = 32768 / (15 * bi);
      sc = sc < 1 ? 1 : (sc > PMAX ? PMAX : sc);
      scale[b * K_ + kk] = sc;
      m[bi] = -1e30f;
    }
    __syncthreads();
  }
}

// ---------------- Kernel C: single-barrier wave scan + windowed means ---------
// grid = B_*N_/ROWS = 2048, block = 256 (4 waves, one (b,n) row per wave).
__global__ __launch_bounds__(256) void trend_kernel(const float* __restrict__ x,
                                                    const int* __restrict__ scale,
                                                    float* __restrict__ out) {
  const int w = threadIdx.x >> 6;
  const int lane = threadIdx.x & 63;
  const int bn = blockIdx.x * ROWS + w;  // b*64 + n
  const int b = bn >> 6;

  __shared__ double P[ROWS][T_ + 1];  // 16.4 KB

  const float* src = x + ((size_t)bn << 9);
  const float4 v0 = *reinterpret_cast<const float4*>(src + (lane << 3));
  const float4 v1 = *reinterpret_cast<const float4*>(src + (lane << 3) + 4);

  double e0 = (double)v0.x;
  double e1 = e0 + (double)v0.y;
  double e2 = e1 + (double)v0.z;
  double e3 = e2 + (double)v0.w;
  double e4 = e3 + (double)v1.x;
  double e5 = e4 + (double)v1.y;
  double e6 = e5 + (double)v1.z;
  double e7 = e6 + (double)v1.w;  // inclusive prefix within the 8-chunk

  double v = e7;
  for (int off = 1; off < 64; off <<= 1) {
    const double o = __shfl_up(v, off);
    if (lane >= off) v += o;
  }
  const double base = v - e7;  // exclusive prefix of this lane's chunk

  double* Pw = P[w];
  if (lane == 0) Pw[0] = 0.0;
  const int p0 = (lane << 3) + 1;
  Pw[p0 + 0] = base + e0;
  Pw[p0 + 1] = base + e1;
  Pw[p0 + 2] = base + e2;
  Pw[p0 + 3] = base + e3;
  Pw[p0 + 4] = base + e4;
  Pw[p0 + 5] = base + e5;
  Pw[p0 + 6] = base + e6;
  Pw[p0 + 7] = base + e7;
  __syncthreads();

  const double x0 = Pw[1];
  const double xl = Pw[T_] - Pw[T_ - 1];

  float* outbn = out + (((size_t)bn * K_) << 9);
#pragma unroll
  for (int kk = 0; kk < K_; ++kk) {
    const int k = scale[b * K_ + kk];
    const int p = (k - 1) >> 1;
    const int Lm1 = T_ + 2 * p - k;  // L - 1
    const double invk = 1.0 / (double)k;
#pragma unroll
    for (int u = 0; u < 8; ++u) {
      const int t = lane + (u << 6);
      const int tc = t < Lm1 ? t : Lm1;
      const int lo = tc - p;       // window = [lo, lo+k) in original coords
      const int hi = lo + k;
      const int cl = lo < 0 ? -lo : 0;        // left edge replications of x[0]
      const int cr = hi > T_ ? hi - T_ : 0;   // right edge replications of x[511]
      const int loc = lo < 0 ? 0 : lo;
      const int hic = hi > T_ ? T_ : hi;
      const double sum = Pw[hic] - Pw[loc] + (double)cl * x0 + (double)cr * xl;
      outbn[(kk << 9) + t] = (float)(sum * invk);
    }
  }
}

}  // namespace

extern "C" void kernel_launch(void* const* d_in, const int* in_sizes, int n_in,
                              void* d_out, int out_size, void* d_ws, size_t ws_size,
                              hipStream_t stream) {
  const float* x = (const float*)d_in[0];
  float* out = (float*)d_out;

  // mag partials in d_out (1024*257 floats = 1.05 MB); trend_kernel fully
  // overwrites d_out afterwards in stream order, so this is safe scratch.
  float* magp = out;
  int* scale = (int*)d_ws;  // 2.5 KB, must survive while C runs

  hipLaunchKernelGGL(fft_mag_kernel, dim3(B_ * N_ / FROWS), dim3(256), 0, stream, x, magp);
  hipLaunchKernelGGL(topk_scale_kernel, dim3(B_), dim3(64), 0, stream, magp, scale);
  hipLaunchKernelGGL(trend_kernel, dim3(B_ * N_ / ROWS), dim3(256), 0, stream, x, scale, out);
}

// Round 10
// 38.032 us; speedup vs baseline: 1.2118x; 1.1069x over previous
//
#include <hip/hip_runtime.h>
#include <cmath>

namespace {

constexpr int B_ = 128;
constexpr int N_ = 64;
constexpr int T_ = 512;
constexpr int K_ = 5;
constexpr int NBINS = 257;   // T/2 + 1
constexpr int PMAX = 2184;   // T*T // 120
constexpr int ROWS = 4;      // trend: (b,n) rows per block, 1 per wave
constexpr int FROWS = 8;     // fft: rows per block (2 per wave)
constexpr int CHUNKS = N_ / FROWS;  // 8 mag-partial chunks per batch

struct cpx { float re, im; };
__device__ __forceinline__ cpx cadd(cpx a, cpx b) { return {a.re + b.re, a.im + b.im}; }
__device__ __forceinline__ cpx csub(cpx a, cpx b) { return {a.re - b.re, a.im - b.im}; }
__device__ __forceinline__ cpx cmul(cpx a, cpx b) {
  return {a.re * b.re - a.im * b.im, a.re * b.im + a.im * b.re};
}

// Full complex radix-8 DFT on named scalars. t_c = sum_w z_w * W8^{w*c}.
__device__ __forceinline__ void radix8(
    cpx z0, cpx z1, cpx z2, cpx z3, cpx z4, cpx z5, cpx z6, cpx z7,
    cpx& t0, cpx& t1, cpx& t2, cpx& t3, cpx& t4, cpx& t5, cpx& t6, cpx& t7) {
  const float c = 0.70710678118654752f;
  cpx a0 = cadd(z0, z4), a1 = csub(z0, z4);
  cpx a2 = cadd(z2, z6), a3 = csub(z2, z6);
  cpx a4 = cadd(z1, z5), a5 = csub(z1, z5);
  cpx a6 = cadd(z3, z7), a7 = csub(z3, z7);
  cpx b0 = cadd(a0, a2), b1 = csub(a0, a2);
  cpx b2 = cadd(a4, a6), b3 = csub(a4, a6);
  t0 = cadd(b0, b2);
  t4 = csub(b0, b2);
  t2 = {b1.re + b3.im, b1.im - b3.re};   // b1 - i*b3
  t6 = {b1.re - b3.im, b1.im + b3.re};   // b1 + i*b3
  cpx ua5  = {c * (a5.re + a5.im), c * (a5.im - a5.re)};  // u*a5,  u = c(1-i)
  cpx usa5 = {c * (a5.re - a5.im), c * (a5.re + a5.im)};  // u"*a5, u" = c(1+i)
  cpx ua7  = {c * (a7.re + a7.im), c * (a7.im - a7.re)};
  cpx usa7 = {c * (a7.re - a7.im), c * (a7.re + a7.im)};
  cpx mia3 = {a3.im, -a3.re};
  cpx pia3 = {-a3.im, a3.re};
  t1 = cadd(cadd(a1, ua5), csub(mia3, usa7));
  t3 = cadd(csub(a1, usa5), cadd(pia3, ua7));
  t5 = cadd(csub(a1, ua5), cadd(mia3, usa7));
  t7 = cadd(cadd(a1, usa5), csub(pia3, ua7));
}

// Phase-1 real radix-8 + W512^{jr} twiddle + store to plane (SoA stride 9).
__device__ __forceinline__ void p1_row(const float* __restrict__ src, int j,
                                       cpx wj, float* __restrict__ br,
                                       float* __restrict__ bi) {
  const float x0v = src[j], x1v = src[j + 64], x2v = src[j + 128], x3v = src[j + 192];
  const float x4v = src[j + 256], x5v = src[j + 320], x6v = src[j + 384], x7v = src[j + 448];
  const float c = 0.70710678118654752f;
  const float s04 = x0v + x4v, d04 = x0v - x4v;
  const float s26 = x2v + x6v, d26 = x2v - x6v;
  const float s15 = x1v + x5v, d15 = x1v - x5v;
  const float s37 = x3v + x7v, d37 = x3v - x7v;
  const float se = s04 + s26, so = s15 + s37;
  const float cm = c * (d15 - d37), cp = c * (d15 + d37);
  const cpx y0 = {se + so, 0.f};
  const cpx y1 = {d04 + cm, -(d26 + cp)};
  const cpx y2 = {s04 - s26, s37 - s15};
  const cpx y3 = {d04 - cm, d26 - cp};
  const cpx y4 = {se - so, 0.f};
  const cpx y5 = {d04 - cm, cp - d26};   // conj(y3)
  const cpx y6 = {s04 - s26, s15 - s37}; // conj(y2)
  const cpx y7 = {d04 + cm, d26 + cp};   // conj(y1)
  const int p = j * 9;
  cpx tw = wj, z;
  br[p + 0] = y0.re;              bi[p + 0] = y0.im;
  z = cmul(y1, tw); br[p + 1] = z.re; bi[p + 1] = z.im; tw = cmul(tw, wj);
  z = cmul(y2, tw); br[p + 2] = z.re; bi[p + 2] = z.im; tw = cmul(tw, wj);
  z = cmul(y3, tw); br[p + 3] = z.re; bi[p + 3] = z.im; tw = cmul(tw, wj);
  z = cmul(y4, tw); br[p + 4] = z.re; bi[p + 4] = z.im; tw = cmul(tw, wj);
  z = cmul(y5, tw); br[p + 5] = z.re; bi[p + 5] = z.im; tw = cmul(tw, wj);
  z = cmul(y6, tw); br[p + 6] = z.re; bi[p + 6] = z.im; tw = cmul(tw, wj);
  z = cmul(y7, tw); br[p + 7] = z.re; bi[p + 7] = z.im;
}

// Phase-2: read stride-72 column, radix-8, W64^{ic} twiddle, write transposed.
__device__ __forceinline__ void p2_row(int r2, int i2, cpx wi,
                                       float* __restrict__ br,
                                       float* __restrict__ bi) {
  const int p = i2 * 9 + r2;
  const cpx zz0 = {br[p +   0], bi[p +   0]};
  const cpx zz1 = {br[p +  72], bi[p +  72]};
  const cpx zz2 = {br[p + 144], bi[p + 144]};
  const cpx zz3 = {br[p + 216], bi[p + 216]};
  const cpx zz4 = {br[p + 288], bi[p + 288]};
  const cpx zz5 = {br[p + 360], bi[p + 360]};
  const cpx zz6 = {br[p + 432], bi[p + 432]};
  const cpx zz7 = {br[p + 504], bi[p + 504]};
  cpx t0, t1, t2, t3, t4, t5, t6, t7;
  radix8(zz0, zz1, zz2, zz3, zz4, zz5, zz6, zz7, t0, t1, t2, t3, t4, t5, t6, t7);
  cpx tw = wi;
  cpx y1 = cmul(t1, tw); tw = cmul(tw, wi);
  cpx y2 = cmul(t2, tw); tw = cmul(tw, wi);
  cpx y3 = cmul(t3, tw); tw = cmul(tw, wi);
  cpx y4 = cmul(t4, tw); tw = cmul(tw, wi);
  cpx y5 = cmul(t5, tw); tw = cmul(tw, wi);
  cpx y6 = cmul(t6, tw); tw = cmul(tw, wi);
  cpx y7 = cmul(t7, tw);
  // write y_c at (r2*8+c)*9 + i2 ; within-wave RAW/WAR ordered by lgkmcnt
  const int q = r2 * 72 + i2;
  br[q +  0] = t0.re; bi[q +  0] = t0.im;
  br[q +  9] = y1.re; bi[q +  9] = y1.im;
  br[q + 18] = y2.re; bi[q + 18] = y2.im;
  br[q + 27] = y3.re; bi[q + 27] = y3.im;
  br[q + 36] = y4.re; bi[q + 36] = y4.im;
  br[q + 45] = y5.re; bi[q + 45] = y5.im;
  br[q + 54] = y6.re; bi[q + 54] = y6.im;
  br[q + 63] = y7.re; bi[q + 63] = y7.im;
}

// Phase-3: final radix-8 -> |X| for k = 64s + 8c + r, k <= 256.
__device__ __forceinline__ void p3_row(int r3, int c3,
                                       const float* __restrict__ br,
                                       const float* __restrict__ bi,
                                       float& m0, float& m1, float& m2,
                                       float& m3, float& m4) {
  const int p = r3 * 72 + c3 * 9;
  const cpx yy0 = {br[p + 0], bi[p + 0]};
  const cpx yy1 = {br[p + 1], bi[p + 1]};
  const cpx yy2 = {br[p + 2], bi[p + 2]};
  const cpx yy3 = {br[p + 3], bi[p + 3]};
  const cpx yy4 = {br[p + 4], bi[p + 4]};
  const cpx yy5 = {br[p + 5], bi[p + 5]};
  const cpx yy6 = {br[p + 6], bi[p + 6]};
  const cpx yy7 = {br[p + 7], bi[p + 7]};
  cpx X0, X1, X2, X3, X4, X5, X6, X7;
  radix8(yy0, yy1, yy2, yy3, yy4, yy5, yy6, yy7, X0, X1, X2, X3, X4, X5, X6, X7);
  m0 = sqrtf(X0.re * X0.re + X0.im * X0.im);
  m1 = sqrtf(X1.re * X1.re + X1.im * X1.im);
  m2 = sqrtf(X2.re * X2.re + X2.im * X2.im);
  m3 = sqrtf(X3.re * X3.re + X3.im * X3.im);
  m4 = sqrtf(X4.re * X4.re + X4.im * X4.im);
}

// ---------------- Kernel A: radix-8^3 FFT magnitudes, 2 rows/wave -------------
// grid = B_*N_/FROWS = 1024, block = 256 (4 waves, 2 rows each).
// Waves own LDS planes exclusively -> single barrier before the cross-wave sum.
__global__ __launch_bounds__(256, 4) void fft_mag_kernel(const float* __restrict__ x,
                                                         float* __restrict__ magp) {
  const int tid = threadIdx.x;
  const int w = tid >> 6;
  const int lane = tid & 63;
  const int rowA = blockIdx.x * FROWS + 2 * w;  // b*64 + n

  __shared__ float bre[FROWS][576];
  __shared__ float bim[FROWS][576];

  float* brA = &bre[2 * w][0];
  float* biA = &bim[2 * w][0];
  float* brB = &bre[2 * w + 1][0];
  float* biB = &bim[2 * w + 1][0];

  const float* srcA = x + ((size_t)rowA << 9);
  const float* srcB = srcA + T_;

  // phase 1 (shared twiddle W512^j)
  {
    float sj, cj;
    __sincosf((float)lane * 0.01227184630308513f /*2pi/512*/, &sj, &cj);
    const cpx wj = {cj, -sj};
    p1_row(srcA, lane, wj, brA, biA);
    p1_row(srcB, lane, wj, brB, biB);
  }

  // phase 2 (shared twiddle W64^i)
  const int r2 = lane >> 3, i2 = lane & 7;
  {
    float si, ci;
    __sincosf((float)i2 * 0.09817477042468103f /*2pi/64*/, &si, &ci);
    const cpx wi = {ci, -si};
    p2_row(r2, i2, wi, brA, biA);
    p2_row(r2, i2, wi, brB, biB);
  }

  // phase 3: |X_A| + |X_B| -> even plane [0..256]
  {
    float a0, a1, a2, a3, a4, b0, b1, b2, b3, b4;
    p3_row(r2, i2, brA, biA, a0, a1, a2, a3, a4);
    p3_row(r2, i2, brB, biB, b0, b1, b2, b3, b4);
    const int kb = (i2 << 3) + r2;  // 0..63
    brA[kb +   0] = a0 + b0;
    brA[kb +  64] = a1 + b1;
    brA[kb + 128] = a2 + b2;
    brA[kb + 192] = a3 + b3;
    if (kb == 0) brA[256] = a4 + b4;
  }
  __syncthreads();  // the only cross-wave handoff

  for (int bin = tid; bin < NBINS; bin += 256) {
    magp[(size_t)blockIdx.x * NBINS + bin] =
        bre[0][bin] + bre[2][bin] + bre[4][bin] + bre[6][bin];
  }
}

// ---------------- Kernel B: fused per-block top-k + scan + windowed means -----
// grid = B_*N_/ROWS = 2048, block = 256 (4 waves, one (b,n) row per wave).
// Each block REDUNDANTLY computes its batch's top-5 from magp (published at the
// fft->trend kernel boundary -- the XCD-coherence-safe handoff, cf. R5 race).
// Extraction is all-register in wave 0 (no LDS RMW ordering, no divergent
// barrier) and overlaps waves 1-3's prefix scans; one barrier publishes sc[].
__global__ __launch_bounds__(256) void trend_topk_kernel(const float* __restrict__ x,
                                                         const float* __restrict__ magp,
                                                         float* __restrict__ out) {
  const int tid = threadIdx.x;
  const int w = tid >> 6;
  const int lane = tid & 63;
  const int bn = blockIdx.x * ROWS + w;  // b*64 + n
  const int b = bn >> 6;                 // = blockIdx.x/16: all 4 rows same batch

  __shared__ float m[NBINS];
  __shared__ int sc[K_];
  __shared__ double P[ROWS][T_ + 1];  // 16.4 KB

  // ---- batch magnitude sums (all 256 threads, ~1 bin each)
  for (int i = tid; i < NBINS; i += 256) {
    float s = -1.0f;
    if (i != 0) {
      s = 0.0f;
      const float* mp = magp + (size_t)b * CHUNKS * NBINS + i;
#pragma unroll
      for (int c = 0; c < CHUNKS; ++c) s += mp[c * NBINS];
    }
    m[i] = s;
  }
  __syncthreads();

  // ---- wave 0: all-register top-5 extraction (jax tie-break: lower index)
  if (w == 0) {
    float q0 = m[lane], q1 = m[lane + 64], q2 = m[lane + 128], q3 = m[lane + 192];
    float q4 = (lane == 0) ? m[256] : -1.0e30f;
    const int i0 = lane, i1 = lane + 64, i2x = lane + 128, i3 = lane + 192;
    const int i4 = (lane == 0) ? 256 : NBINS + 1;
#pragma unroll
    for (int kk = 0; kk < K_; ++kk) {
      // within-lane best (indices ascending -> strict > keeps lowest index)
      float bv = q0; int bi = i0;
      if (q1 > bv) { bv = q1; bi = i1; }
      if (q2 > bv) { bv = q2; bi = i2x; }
      if (q3 > bv) { bv = q3; bi = i3; }
      if (q4 > bv) { bv = q4; bi = i4; }
      // cross-lane reduce
      for (int off = 32; off > 0; off >>= 1) {
        const float ov = __shfl_down(bv, off);
        const int oi = __shfl_down(bi, off);
        if (ov > bv || (ov == bv && oi < bi)) { bv = ov; bi = oi; }
      }
      bi = __shfl(bi, 0);
      if (lane == 0) {
        // scale = floor(512 / (i * 15/64)) = 32768 / (15*i), exact integer
        int s = 32768 / (15 * bi);
        s = s < 1 ? 1 : (s > PMAX ? PMAX : s);
        sc[kk] = s;
      }
      // clear the chosen bin (exactly one lane owns it)
      if (bi == i0) q0 = -1.0e30f;
      else if (bi == i1) q1 = -1.0e30f;
      else if (bi == i2x) q2 = -1.0e30f;
      else if (bi == i3) q3 = -1.0e30f;
      else if (bi == i4) q4 = -1.0e30f;
    }
  }

  // ---- per-wave f64 prefix scan of own row (independent of sc)
  const float* src = x + ((size_t)bn << 9);
  const float4 v0 = *reinterpret_cast<const float4*>(src + (lane << 3));
  const float4 v1 = *reinterpret_cast<const float4*>(src + (lane << 3) + 4);

  double e0 = (double)v0.x;
  double e1 = e0 + (double)v0.y;
  double e2 = e1 + (double)v0.z;
  double e3 = e2 + (double)v0.w;
  double e4 = e3 + (double)v1.x;
  double e5 = e4 + (double)v1.y;
  double e6 = e5 + (double)v1.z;
  double e7 = e6 + (double)v1.w;  // inclusive prefix within the 8-chunk

  double v = e7;
  for (int off = 1; off < 64; off <<= 1) {
    const double o = __shfl_up(v, off);
    if (lane >= off) v += o;
  }
  const double base = v - e7;  // exclusive prefix of this lane's chunk

  double* Pw = P[w];
  if (lane == 0) Pw[0] = 0.0;
  const int p0 = (lane << 3) + 1;
  Pw[p0 + 0] = base + e0;
  Pw[p0 + 1] = base + e1;
  Pw[p0 + 2] = base + e2;
  Pw[p0 + 3] = base + e3;
  Pw[p0 + 4] = base + e4;
  Pw[p0 + 5] = base + e5;
  Pw[p0 + 6] = base + e6;
  Pw[p0 + 7] = base + e7;
  __syncthreads();  // publishes sc[] (and own-wave P ordering is free)

  const double x0 = Pw[1];
  const double xl = Pw[T_] - Pw[T_ - 1];

  float* outbn = out + (((size_t)bn * K_) << 9);
#pragma unroll
  for (int kk = 0; kk < K_; ++kk) {
    const int k = sc[kk];
    const int p = (k - 1) >> 1;
    const int Lm1 = T_ + 2 * p - k;  // L - 1
    const double invk = 1.0 / (double)k;
#pragma unroll
    for (int u = 0; u < 8; ++u) {
      const int t = lane + (u << 6);
      const int tc = t < Lm1 ? t : Lm1;
      const int lo = tc - p;       // window = [lo, lo+k) in original coords
      const int hi = lo + k;
      const int cl = lo < 0 ? -lo : 0;        // left edge replications of x[0]
      const int cr = hi > T_ ? hi - T_ : 0;   // right edge replications of x[511]
      const int loc = lo < 0 ? 0 : lo;
      const int hic = hi > T_ ? T_ : hi;
      const double sum = Pw[hic] - Pw[loc] + (double)cl * x0 + (double)cr * xl;
      outbn[(kk << 9) + t] = (float)(sum * invk);
    }
  }
}

}  // namespace

extern "C" void kernel_launch(void* const* d_in, const int* in_sizes, int n_in,
                              void* d_out, int out_size, void* d_ws, size_t ws_size,
                              hipStream_t stream) {
  const float* x = (const float*)d_in[0];
  float* out = (float*)d_out;

  // magp (1024*257 floats = 1.05 MB) lives in d_ws (ws is ~hundreds of MB per
  // the harness poison sizes); fully rewritten by fft each call.
  float* magp = (float*)d_ws;

  hipLaunchKernelGGL(fft_mag_kernel, dim3(B_ * N_ / FROWS), dim3(256), 0, stream, x, magp);
  hipLaunchKernelGGL(trend_topk_kernel, dim3(B_ * N_ / ROWS), dim3(256), 0, stream, x, magp, out);
}

// Round 11
// 32.886 us; speedup vs baseline: 1.4014x; 1.1565x over previous
//
#include <hip/hip_runtime.h>
#include <cmath>

namespace {

constexpr int B_ = 128;
constexpr int N_ = 64;
constexpr int T_ = 512;
constexpr int K_ = 5;
constexpr int NBINS = 257;   // T/2 + 1
constexpr int PMAX = 2184;   // T*T // 120
constexpr int ROWS = 4;      // trend: (b,n) rows per block, 1 per wave
constexpr int FROWS = 8;     // fft: rows per block (2 rows = 1 packed FFT per wave)
constexpr int CHUNKS = N_ / FROWS;  // 8 mag-partial chunks per batch

struct cpx { float re, im; };
__device__ __forceinline__ cpx cadd(cpx a, cpx b) { return {a.re + b.re, a.im + b.im}; }
__device__ __forceinline__ cpx csub(cpx a, cpx b) { return {a.re - b.re, a.im - b.im}; }
__device__ __forceinline__ cpx cmul(cpx a, cpx b) {
  return {a.re * b.re - a.im * b.im, a.re * b.im + a.im * b.re};
}

// Full complex radix-8 DFT on named scalars. t_c = sum_w z_w * W8^{w*c}.
__device__ __forceinline__ void radix8(
    cpx z0, cpx z1, cpx z2, cpx z3, cpx z4, cpx z5, cpx z6, cpx z7,
    cpx& t0, cpx& t1, cpx& t2, cpx& t3, cpx& t4, cpx& t5, cpx& t6, cpx& t7) {
  const float c = 0.70710678118654752f;
  cpx a0 = cadd(z0, z4), a1 = csub(z0, z4);
  cpx a2 = cadd(z2, z6), a3 = csub(z2, z6);
  cpx a4 = cadd(z1, z5), a5 = csub(z1, z5);
  cpx a6 = cadd(z3, z7), a7 = csub(z3, z7);
  cpx b0 = cadd(a0, a2), b1 = csub(a0, a2);
  cpx b2 = cadd(a4, a6), b3 = csub(a4, a6);
  t0 = cadd(b0, b2);
  t4 = csub(b0, b2);
  t2 = {b1.re + b3.im, b1.im - b3.re};   // b1 - i*b3
  t6 = {b1.re - b3.im, b1.im + b3.re};   // b1 + i*b3
  cpx ua5  = {c * (a5.re + a5.im), c * (a5.im - a5.re)};  // u*a5,  u = c(1-i)
  cpx usa5 = {c * (a5.re - a5.im), c * (a5.re + a5.im)};  // u"*a5, u" = c(1+i)
  cpx ua7  = {c * (a7.re + a7.im), c * (a7.im - a7.re)};
  cpx usa7 = {c * (a7.re - a7.im), c * (a7.re + a7.im)};
  cpx mia3 = {a3.im, -a3.re};
  cpx pia3 = {-a3.im, a3.re};
  t1 = cadd(cadd(a1, ua5), csub(mia3, usa7));
  t3 = cadd(csub(a1, usa5), cadd(pia3, ua7));
  t5 = cadd(csub(a1, ua5), cadd(mia3, usa7));
  t7 = cadd(cadd(a1, usa5), csub(pia3, ua7));
}

__device__ __forceinline__ void lds_fence() {
  // Cross-lane LDS read->write hazards are invisible to per-lane alias
  // analysis; pin instruction order at phase boundaries (compile-time only).
  __builtin_amdgcn_sched_barrier(0);
}

// ---------------- Kernel A: packed radix-8^3 FFT magnitudes -------------------
// grid = B_*N_/FROWS = 1024, block = 256 (4 waves; each wave packs 2 real rows
// into ONE complex FFT: z = a + i*b; unpack |A|,|B| via conjugate symmetry).
// Waves own their LDS plane exclusively -> no barriers until the final sum.
__global__ __launch_bounds__(256, 4) void fft_mag_kernel(const float* __restrict__ x,
                                                         float* __restrict__ magp) {
  const int tid = threadIdx.x;
  const int w = tid >> 6;
  const int lane = tid & 63;
  const int rowA = blockIdx.x * FROWS + 2 * w;  // b*64 + n

  __shared__ float bre[4][576];   // one plane pair per wave, stride-9 rows
  __shared__ float bim[4][576];

  float* br = &bre[w][0];
  float* bi = &bim[w][0];

  const float* srcA = x + ((size_t)rowA << 9);
  const float* srcB = srcA + T_;

  // ---- phase 1: complex radix-8 over v (stride 64) + twiddle W512^{j*r}
  {
    const int j = lane;
    const cpx z0 = {srcA[j],       srcB[j]};
    const cpx z1 = {srcA[j +  64], srcB[j +  64]};
    const cpx z2 = {srcA[j + 128], srcB[j + 128]};
    const cpx z3 = {srcA[j + 192], srcB[j + 192]};
    const cpx z4 = {srcA[j + 256], srcB[j + 256]};
    const cpx z5 = {srcA[j + 320], srcB[j + 320]};
    const cpx z6 = {srcA[j + 384], srcB[j + 384]};
    const cpx z7 = {srcA[j + 448], srcB[j + 448]};
    cpx y0, y1, y2, y3, y4, y5, y6, y7;
    radix8(z0, z1, z2, z3, z4, z5, z6, z7, y0, y1, y2, y3, y4, y5, y6, y7);
    float sj, cj;
    __sincosf((float)j * 0.01227184630308513f /*2pi/512*/, &sj, &cj);
    const cpx wj = {cj, -sj};
    const int p = j * 9;
    cpx tw = wj, z;
    br[p + 0] = y0.re;            bi[p + 0] = y0.im;
    z = cmul(y1, tw); br[p + 1] = z.re; bi[p + 1] = z.im; tw = cmul(tw, wj);
    z = cmul(y2, tw); br[p + 2] = z.re; bi[p + 2] = z.im; tw = cmul(tw, wj);
    z = cmul(y3, tw); br[p + 3] = z.re; bi[p + 3] = z.im; tw = cmul(tw, wj);
    z = cmul(y4, tw); br[p + 4] = z.re; bi[p + 4] = z.im; tw = cmul(tw, wj);
    z = cmul(y5, tw); br[p + 5] = z.re; bi[p + 5] = z.im; tw = cmul(tw, wj);
    z = cmul(y6, tw); br[p + 6] = z.re; bi[p + 6] = z.im; tw = cmul(tw, wj);
    z = cmul(y7, tw); br[p + 7] = z.re; bi[p + 7] = z.im;
  }
  lds_fence();

  // ---- phase 2: complex radix-8 over w (stride 8) + twiddle W64^{i*c}
  const int r2 = lane >> 3, i2 = lane & 7;
  {
    const int p = i2 * 9 + r2;
    const cpx zz0 = {br[p +   0], bi[p +   0]};
    const cpx zz1 = {br[p +  72], bi[p +  72]};
    const cpx zz2 = {br[p + 144], bi[p + 144]};
    const cpx zz3 = {br[p + 216], bi[p + 216]};
    const cpx zz4 = {br[p + 288], bi[p + 288]};
    const cpx zz5 = {br[p + 360], bi[p + 360]};
    const cpx zz6 = {br[p + 432], bi[p + 432]};
    const cpx zz7 = {br[p + 504], bi[p + 504]};
    cpx t0, t1, t2, t3, t4, t5, t6, t7;
    radix8(zz0, zz1, zz2, zz3, zz4, zz5, zz6, zz7, t0, t1, t2, t3, t4, t5, t6, t7);
    float si, ci;
    __sincosf((float)i2 * 0.09817477042468103f /*2pi/64*/, &si, &ci);
    const cpx wi = {ci, -si};
    cpx tw = wi;
    cpx y1 = cmul(t1, tw); tw = cmul(tw, wi);
    cpx y2 = cmul(t2, tw); tw = cmul(tw, wi);
    cpx y3 = cmul(t3, tw); tw = cmul(tw, wi);
    cpx y4 = cmul(t4, tw); tw = cmul(tw, wi);
    cpx y5 = cmul(t5, tw); tw = cmul(tw, wi);
    cpx y6 = cmul(t6, tw); tw = cmul(tw, wi);
    cpx y7 = cmul(t7, tw);
    lds_fence();  // all phase-2 reads before transposed writes
    const int q = r2 * 72 + i2;
    br[q +  0] = t0.re; bi[q +  0] = t0.im;
    br[q +  9] = y1.re; bi[q +  9] = y1.im;
    br[q + 18] = y2.re; bi[q + 18] = y2.im;
    br[q + 27] = y3.re; bi[q + 27] = y3.im;
    br[q + 36] = y4.re; bi[q + 36] = y4.im;
    br[q + 45] = y5.re; bi[q + 45] = y5.im;
    br[q + 54] = y6.re; bi[q + 54] = y6.im;
    br[q + 63] = y7.re; bi[q + 63] = y7.im;
  }
  lds_fence();

  // ---- phase 3: final radix-8 over i -> Z[64s + 8c + r], write FULL Z (512)
  {
    const int r3 = lane >> 3, c3 = lane & 7;
    const int p = r3 * 72 + c3 * 9;
    const cpx yy0 = {br[p + 0], bi[p + 0]};
    const cpx yy1 = {br[p + 1], bi[p + 1]};
    const cpx yy2 = {br[p + 2], bi[p + 2]};
    const cpx yy3 = {br[p + 3], bi[p + 3]};
    const cpx yy4 = {br[p + 4], bi[p + 4]};
    const cpx yy5 = {br[p + 5], bi[p + 5]};
    const cpx yy6 = {br[p + 6], bi[p + 6]};
    const cpx yy7 = {br[p + 7], bi[p + 7]};
    cpx X0, X1, X2, X3, X4, X5, X6, X7;
    radix8(yy0, yy1, yy2, yy3, yy4, yy5, yy6, yy7, X0, X1, X2, X3, X4, X5, X6, X7);
    lds_fence();  // all phase-3 reads before Z writes
    const int kb0 = (c3 << 3) + r3;  // Z index base; Z[kb0 + 64s] = X_s
    br[kb0 +   0] = X0.re; bi[kb0 +   0] = X0.im;
    br[kb0 +  64] = X1.re; bi[kb0 +  64] = X1.im;
    br[kb0 + 128] = X2.re; bi[kb0 + 128] = X2.im;
    br[kb0 + 192] = X3.re; bi[kb0 + 192] = X3.im;
    br[kb0 + 256] = X4.re; bi[kb0 + 256] = X4.im;
    br[kb0 + 320] = X5.re; bi[kb0 + 320] = X5.im;
    br[kb0 + 384] = X6.re; bi[kb0 + 384] = X6.im;
    br[kb0 + 448] = X7.re; bi[kb0 + 448] = X7.im;
  }
  lds_fence();

  // ---- unpack: |A[k]|+|B[k]| from Z[k], Z[512-k]; mags overwrite br[0..256]
  {
    // k = lane + 64u, u = 0..3 (+ k=256 handled by lane 0)
    float m[4];
    float a0, b0, c0, d0, a1, b1, c1, d1, a2, b2, c2, d2, a3, b3, c3v, d3;
    {
      const int k0 = lane, k0m = (512 - k0) & 511;
      a0 = br[k0]; b0 = bi[k0]; c0 = br[k0m]; d0 = bi[k0m];
      const int k1 = lane + 64, k1m = 512 - k1;
      a1 = br[k1]; b1 = bi[k1]; c1 = br[k1m]; d1 = bi[k1m];
      const int k2 = lane + 128, k2m = 512 - k2;
      a2 = br[k2]; b2 = bi[k2]; c2 = br[k2m]; d2 = bi[k2m];
      const int k3 = lane + 192, k3m = 512 - k3;
      a3 = br[k3]; b3 = bi[k3]; c3v = br[k3m]; d3 = bi[k3m];
    }
    float e256r = 0.f, e256i = 0.f;
    if (lane == 0) { e256r = br[256]; e256i = bi[256]; }
    lds_fence();  // ALL unpack reads before mag writes
    {
      const float sa = a0 + c0, dv = b0 - d0, sv = b0 + d0, du = a0 - c0;
      m[0] = 0.5f * (sqrtf(sa * sa + dv * dv) + sqrtf(sv * sv + du * du));
    }
    {
      const float sa = a1 + c1, dv = b1 - d1, sv = b1 + d1, du = a1 - c1;
      m[1] = 0.5f * (sqrtf(sa * sa + dv * dv) + sqrtf(sv * sv + du * du));
    }
    {
      const float sa = a2 + c2, dv = b2 - d2, sv = b2 + d2, du = a2 - c2;
      m[2] = 0.5f * (sqrtf(sa * sa + dv * dv) + sqrtf(sv * sv + du * du));
    }
    {
      const float sa = a3 + c3v, dv = b3 - d3, sv = b3 + d3, du = a3 - c3v;
      m[3] = 0.5f * (sqrtf(sa * sa + dv * dv) + sqrtf(sv * sv + du * du));
    }
    br[lane]       = m[0];
    br[lane + 64]  = m[1];
    br[lane + 128] = m[2];
    br[lane + 192] = m[3];
    if (lane == 0) br[256] = fabsf(e256r) + fabsf(e256i);  // self-paired bin
  }
  __syncthreads();  // the only cross-wave handoff

  for (int bin = tid; bin < NBINS; bin += 256) {
    magp[(size_t)blockIdx.x * NBINS + bin] =
        bre[0][bin] + bre[1][bin] + bre[2][bin] + bre[3][bin];
  }
}

// ---------------- Kernel B: fused per-block top-k + f32 scan + windows --------
// grid = B_*N_/ROWS = 2048, block = 256 (4 waves, one (b,n) row per wave).
// f32 prefix P: abs error <= ~1e-4 << 4.6e-2 threshold (reference is f32 too).
__global__ __launch_bounds__(256) void trend_topk_kernel(const float* __restrict__ x,
                                                         const float* __restrict__ magp,
                                                         float* __restrict__ out) {
  const int tid = threadIdx.x;
  const int w = tid >> 6;
  const int lane = tid & 63;
  const int bn = blockIdx.x * ROWS + w;  // b*64 + n
  const int b = bn >> 6;                 // all 4 rows same batch

  __shared__ float m[NBINS];
  __shared__ int sc[K_];
  __shared__ float P[ROWS][T_ + 1];  // 8.2 KB

  // ---- batch magnitude sums
  for (int i = tid; i < NBINS; i += 256) {
    float s = -1.0f;
    if (i != 0) {
      s = 0.0f;
      const float* mp = magp + (size_t)b * CHUNKS * NBINS + i;
#pragma unroll
      for (int c = 0; c < CHUNKS; ++c) s += mp[c * NBINS];
    }
    m[i] = s;
  }
  __syncthreads();

  // ---- wave 0: all-register top-5 (jax tie-break: lower index)
  if (w == 0) {
    float q0 = m[lane], q1 = m[lane + 64], q2 = m[lane + 128], q3 = m[lane + 192];
    float q4 = (lane == 0) ? m[256] : -1.0e30f;
    const int i0 = lane, i1 = lane + 64, i2x = lane + 128, i3 = lane + 192;
    const int i4 = (lane == 0) ? 256 : NBINS + 1;
#pragma unroll
    for (int kk = 0; kk < K_; ++kk) {
      float bv = q0; int bi = i0;
      if (q1 > bv) { bv = q1; bi = i1; }
      if (q2 > bv) { bv = q2; bi = i2x; }
      if (q3 > bv) { bv = q3; bi = i3; }
      if (q4 > bv) { bv = q4; bi = i4; }
      for (int off = 32; off > 0; off >>= 1) {
        const float ov = __shfl_down(bv, off);
        const int oi = __shfl_down(bi, off);
        if (ov > bv || (ov == bv && oi < bi)) { bv = ov; bi = oi; }
      }
      bi = __shfl(bi, 0);
      if (lane == 0) {
        // scale = floor(512 / (i * 15/64)) = 32768 / (15*i), exact integer
        int s = 32768 / (15 * bi);
        s = s < 1 ? 1 : (s > PMAX ? PMAX : s);
        sc[kk] = s;
      }
      if (bi == i0) q0 = -1.0e30f;
      else if (bi == i1) q1 = -1.0e30f;
      else if (bi == i2x) q2 = -1.0e30f;
      else if (bi == i3) q3 = -1.0e30f;
      else if (bi == i4) q4 = -1.0e30f;
    }
  }

  // ---- per-wave f32 prefix scan of own row
  const float* src = x + ((size_t)bn << 9);
  const float4 v0 = *reinterpret_cast<const float4*>(src + (lane << 3));
  const float4 v1 = *reinterpret_cast<const float4*>(src + (lane << 3) + 4);

  float e0 = v0.x;
  float e1 = e0 + v0.y;
  float e2 = e1 + v0.z;
  float e3 = e2 + v0.w;
  float e4 = e3 + v1.x;
  float e5 = e4 + v1.y;
  float e6 = e5 + v1.z;
  float e7 = e6 + v1.w;  // inclusive prefix within the 8-chunk

  float v = e7;
  for (int off = 1; off < 64; off <<= 1) {
    const float o = __shfl_up(v, off);
    if (lane >= off) v += o;
  }
  const float base = v - e7;  // exclusive prefix of this lane's chunk

  float* Pw = P[w];
  if (lane == 0) Pw[0] = 0.0f;
  const int p0 = (lane << 3) + 1;
  Pw[p0 + 0] = base + e0;
  Pw[p0 + 1] = base + e1;
  Pw[p0 + 2] = base + e2;
  Pw[p0 + 3] = base + e3;
  Pw[p0 + 4] = base + e4;
  Pw[p0 + 5] = base + e5;
  Pw[p0 + 6] = base + e6;
  Pw[p0 + 7] = base + e7;
  __syncthreads();  // publishes sc[] and P

  const float x0 = Pw[1];
  const float xl = Pw[T_] - Pw[T_ - 1];

  float* outbn = out + (((size_t)bn * K_) << 9);
#pragma unroll
  for (int kk = 0; kk < K_; ++kk) {
    const int k = sc[kk];
    const int p = (k - 1) >> 1;
    const int Lm1 = T_ + 2 * p - k;  // L - 1
    const float invk = 1.0f / (float)k;
#pragma unroll
    for (int u = 0; u < 8; ++u) {
      const int t = lane + (u << 6);
      const int tc = t < Lm1 ? t : Lm1;
      const int lo = tc - p;       // window = [lo, lo+k) in original coords
      const int hi = lo + k;
      const int cl = lo < 0 ? -lo : 0;        // left edge replications of x[0]
      const int cr = hi > T_ ? hi - T_ : 0;   // right edge replications of x[511]
      const int loc = lo < 0 ? 0 : lo;
      const int hic = hi > T_ ? T_ : hi;
      const float sum = Pw[hic] - Pw[loc] + (float)cl * x0 + (float)cr * xl;
      outbn[(kk << 9) + t] = sum * invk;
    }
  }
}

}  // namespace

extern "C" void kernel_launch(void* const* d_in, const int* in_sizes, int n_in,
                              void* d_out, int out_size, void* d_ws, size_t ws_size,
                              hipStream_t stream) {
  const float* x = (const float*)d_in[0];
  float* out = (float*)d_out;

  // magp (1024*257 floats = 1.05 MB) lives in d_ws; fully rewritten each call.
  float* magp = (float*)d_ws;

  hipLaunchKernelGGL(fft_mag_kernel, dim3(B_ * N_ / FROWS), dim3(256), 0, stream, x, magp);
  hipLaunchKernelGGL(trend_topk_kernel, dim3(B_ * N_ / ROWS), dim3(256), 0, stream, x, magp, out);
}